// Round 14
// baseline (309.848 us; speedup 1.0000x reference)
//
#include <hip/hip_runtime.h>
#include <hip/hip_bf16.h>
#include <math.h>

// Problem constants
static constexpr int BB = 4;     // batch
static constexpr int CC = 256;   // channels
static constexpr int NN = 4096;  // pixels (64*64)

using bf16   = __bf16;
using f16    = _Float16;
using bf16x8 = __attribute__((ext_vector_type(8))) __bf16;
using bf16x4 = __attribute__((ext_vector_type(4))) __bf16;
using f16x8  = __attribute__((ext_vector_type(8))) _Float16;
using f16x4  = __attribute__((ext_vector_type(4))) _Float16;
using f32x4  = __attribute__((ext_vector_type(4))) float;

// async global->LDS, 16B per lane (dest must be wave-uniform base + lane*16)
__device__ inline void gload_lds16(const void* g, void* l) {
  __builtin_amdgcn_global_load_lds(
      (const __attribute__((address_space(1))) void*)g,
      (__attribute__((address_space(3))) void*)l, 16, 0, 0);
}

// XCD-aware bijective block remap (requires nwg % 8 == 0; all call sites OK).
__device__ inline void swz_bid(int& xb, int& yb, int& zb) {
  int gx = gridDim.x, gy = gridDim.y;
  int nwg = gx * gy * (int)gridDim.z;
  int flat = blockIdx.x + gx * (blockIdx.y + gy * blockIdx.z);
  int q = nwg >> 3;
  int w = (flat & 7) * q + (flat >> 3);
  xb = w % gx;
  int r = w / gx;
  yb = r % gy;
  zb = r / gy;
}

// ---------------------------------------------------------------------------
// all four weight matrices fp32 -> bf16 in one launch. grid (64, 4)
// ---------------------------------------------------------------------------
__global__ __launch_bounds__(256) void cvt_weights_kernel(
    const float* __restrict__ w0, const float* __restrict__ w1,
    const float* __restrict__ w2, const float* __restrict__ w3,
    bf16* __restrict__ out) {
  const float* srcs[4] = {w0, w1, w2, w3};
  const float* s = srcs[blockIdx.y];
  bf16* dst = out + (size_t)blockIdx.y * (CC * CC);
  int i = (blockIdx.x * 256 + threadIdx.x) * 4;
  float4 v = *(const float4*)(s + i);
  bf16x4 t;
  t[0] = (bf16)v.x; t[1] = (bf16)v.y; t[2] = (bf16)v.z; t[3] = (bf16)v.w;
  *(bf16x4*)(dst + i) = t;
}

// ---------------------------------------------------------------------------
// transpose x [B][C][N] fp32 -> xt [B][N][C] bf16
// ---------------------------------------------------------------------------
__global__ __launch_bounds__(256) void transpose_x_kernel(
    const float* __restrict__ x, bf16* __restrict__ xt) {
  __shared__ float tile[64][65];
  int b  = blockIdx.z;
  int c0 = blockIdx.x * 64;
  int n0 = blockIdx.y * 64;
  const float* xp = x  + (long)b * CC * NN;
  bf16*       xtp = xt + (long)b * NN * CC;
  int tj = threadIdx.x & 63;
  int ti = threadIdx.x >> 6;
#pragma unroll
  for (int p = 0; p < 16; ++p) {
    int i = ti + p * 4;
    tile[i][tj] = xp[(long)(c0 + i) * NN + n0 + tj];
  }
  __syncthreads();
#pragma unroll
  for (int p = 0; p < 16; ++p) {
    int i = ti + p * 4;
    xtp[(long)(n0 + i) * CC + c0 + tj] = (bf16)tile[tj][i];
  }
}

// ---------------------------------------------------------------------------
// Fused 4-projection GEMM. blockIdx.z = b*4 + p, p in {0:q,1:ge,2:k,3:v}.
// p==1 reads geo (fp32) directly with reg-staged convert; ge written fp16.
// ---------------------------------------------------------------------------
__global__ __launch_bounds__(256) void proj_all_kernel(
    const bf16* __restrict__ xt, const float* __restrict__ geo,
    const bf16* __restrict__ Wall,
    const float* __restrict__ bq, const float* __restrict__ bgp,
    const float* __restrict__ bk, const float* __restrict__ bv,
    bf16* __restrict__ qn, f16* __restrict__ ge,
    bf16* __restrict__ kn, bf16* __restrict__ vb) {
  __shared__ bf16 As[128 * 32];
  __shared__ bf16 Bs[128 * 32];
  const long NCst = (long)NN * CC;
  const int bz = blockIdx.z;
  const int b = bz >> 2, p = bz & 3;
  const bf16 *Ap = nullptr, *Bp;
  const float* Af32 = nullptr;
  const float* bias;
  int row0, col0;
  if (p == 3) {
    Ap = Wall + 2 * CC * CC;        // Wv
    Bp = xt + b * NCst;
    bias = bv;
    row0 = blockIdx.x * 128;        // M=256
    col0 = blockIdx.y * 128;        // N=4096
  } else {
    if (p == 1) Af32 = geo + b * NCst;
    else        Ap   = xt + b * NCst;
    Bp = Wall + (size_t)(p == 0 ? 0 : (p == 1 ? 3 : 1)) * CC * CC;
    bias = (p == 0 ? bq : (p == 1 ? bgp : bk));
    row0 = blockIdx.y * 128;
    col0 = blockIdx.x * 128;
  }

  const int t   = threadIdx.x;
  const int wid = t >> 6;
  const int l   = t & 63;
  const int lr  = l & 15;
  const int lk  = (l >> 4) * 8;
  const int warow = (wid >> 1) * 64;
  const int wbcol = (wid & 1) * 64;
  const int srow = t >> 2;
  const int scol = (t & 3) * 8;
  const int frow = t >> 3;        // fp32 A staging (p==1)
  const int fc4  = (t & 7) * 4;

  f32x4 acc[4][4];
#pragma unroll
  for (int i = 0; i < 4; ++i)
#pragma unroll
    for (int j = 0; j < 4; ++j) acc[i][j] = {0.f, 0.f, 0.f, 0.f};

  for (int k0 = 0; k0 < CC; k0 += 32) {
    __syncthreads();
    if (p == 1) {
#pragma unroll
      for (int q = 0; q < 4; ++q) {
        float4 u = *(const float4*)(Af32 + (long)(row0 + frow + 32 * q) * CC + k0 + fc4);
        bf16x4 tv;
        tv[0] = (bf16)u.x; tv[1] = (bf16)u.y; tv[2] = (bf16)u.z; tv[3] = (bf16)u.w;
        *(bf16x4*)(As + (frow + 32 * q) * 32 + fc4) = tv;
      }
    } else {
#pragma unroll
      for (int q = 0; q < 2; ++q)
        gload_lds16(Ap + (long)(row0 + srow + 64 * q) * CC + k0 + scol,
                    As + ((q * 256 + t) * 8));
    }
#pragma unroll
    for (int q = 0; q < 2; ++q)
      gload_lds16(Bp + (long)(col0 + srow + 64 * q) * CC + k0 + scol,
                  Bs + ((q * 256 + t) * 8));
    __syncthreads();
    bf16x8 a[4], bb[4];
#pragma unroll
    for (int i = 0; i < 4; ++i)
      a[i] = *(const bf16x8*)(As + (warow + 16 * i + lr) * 32 + lk);
#pragma unroll
    for (int j = 0; j < 4; ++j)
      bb[j] = *(const bf16x8*)(Bs + (wbcol + 16 * j + lr) * 32 + lk);
#pragma unroll
    for (int i = 0; i < 4; ++i)
#pragma unroll
      for (int j = 0; j < 4; ++j)
        acc[i][j] = __builtin_amdgcn_mfma_f32_16x16x32_bf16(a[i], bb[j], acc[i][j], 0, 0, 0);
  }

  const int orow = (l >> 4) * 4;
  const int ocol = l & 15;
#pragma unroll
  for (int i = 0; i < 4; ++i) {
#pragma unroll
    for (int j = 0; j < 4; ++j) {
      int colb = col0 + wbcol + 16 * j + ocol;
#pragma unroll
      for (int r = 0; r < 4; ++r) {
        int row = row0 + warow + 16 * i + orow + r;
        if (p == 3) {
          float vv = acc[i][j][r] + bias[row];
          vb[b * NCst + (long)row * NN + colb] = (bf16)vv;
        } else {
          float vv = acc[i][j][r] + bias[colb];
          long di = b * NCst + (long)row * CC + colb;
          if (p == 1)
            ge[di] = (f16)vv;
          else
            (p == 0 ? qn : kn)[di] = (bf16)vv;
        }
      }
    }
  }
}

// ---------------------------------------------------------------------------
// Energy GEMM: E[r][c] = sum_k q[r][k]*kn[c][k], fp16 out (nontemporal) +
// per-row/128-col softmax partials. 256x128 tile, 8 waves, BK=64, chunk-XOR
// swizzled LDS. grid (32, 16, B).
// ---------------------------------------------------------------------------
template <bool SWZ>
__global__ __launch_bounds__(512) void energy_kernel(
    const bf16* __restrict__ Q, const bf16* __restrict__ K,
    f16* __restrict__ E, float2* __restrict__ pstat) {
  __shared__ bf16 As[256 * 64];     // 32 KB
  __shared__ bf16 Bs[128 * 64];     // 16 KB
  __shared__ float2 sm[256][2];     // 4 KB
  int bx = blockIdx.x, by = blockIdx.y, bz = blockIdx.z;
  if constexpr (SWZ) swz_bid(bx, by, bz);
  const long NCst = (long)NN * CC;
  const long NNst = (long)NN * NN;
  const bf16* Qb = Q + bz * NCst;
  const bf16* Kb = K + bz * NCst;
  f16* Eb = E + bz * NNst;
  const int row0 = by * 256;
  const int col0 = bx * 128;

  const int t   = threadIdx.x;
  const int wid = t >> 6;
  const int l   = t & 63;
  const int lr  = l & 15;
  const int lk8 = l >> 4;           // 0..3
  const int wm  = (wid >> 1) * 64;  // wave M offset (0..192)
  const int wn  = (wid & 1) * 64;   // wave N offset (0/64)

  const int srow = t >> 3;          // 0..63 (staging local row)
  const int schk = t & 7;           // staging chunk

  f32x4 acc[4][4];
#pragma unroll
  for (int i = 0; i < 4; ++i)
#pragma unroll
    for (int j = 0; j < 4; ++j) acc[i][j] = {0.f, 0.f, 0.f, 0.f};

  for (int k0 = 0; k0 < CC; k0 += 64) {
    __syncthreads();
#pragma unroll
    for (int p = 0; p < 4; ++p) {
      int r = srow + 64 * p;
      gload_lds16(Qb + (long)(row0 + r) * CC + k0 + ((schk ^ (r & 7)) * 8),
                  As + ((p * 512 + t) * 8));
    }
#pragma unroll
    for (int p = 0; p < 2; ++p) {
      int r = srow + 64 * p;
      gload_lds16(Kb + (long)(col0 + r) * CC + k0 + ((schk ^ (r & 7)) * 8),
                  Bs + ((p * 512 + t) * 8));
    }
    __syncthreads();
#pragma unroll
    for (int kk = 0; kk < 2; ++kk) {
      bf16x8 a[4], b[4];
#pragma unroll
      for (int i = 0; i < 4; ++i) {
        int Ra = wm + 16 * i + lr;
        a[i] = *(const bf16x8*)(As + Ra * 64 + (((kk * 4 + lk8) ^ (Ra & 7)) * 8));
      }
#pragma unroll
      for (int j = 0; j < 4; ++j) {
        int Rb = wn + 16 * j + lr;
        b[j] = *(const bf16x8*)(Bs + Rb * 64 + (((kk * 4 + lk8) ^ (Rb & 7)) * 8));
      }
#pragma unroll
      for (int i = 0; i < 4; ++i)
#pragma unroll
        for (int j = 0; j < 4; ++j)
          acc[i][j] = __builtin_amdgcn_mfma_f32_16x16x32_bf16(a[i], b[j], acc[i][j], 0, 0, 0);
    }
  }

  const int orow = (l >> 4) * 4;
  const int ocol = l & 15;
#pragma unroll
  for (int i = 0; i < 4; ++i) {
#pragma unroll
    for (int j = 0; j < 4; ++j) {
      int colb = col0 + wn + 16 * j + ocol;
#pragma unroll
      for (int r = 0; r < 4; ++r) {
        int row = row0 + wm + 16 * i + orow + r;
        __builtin_nontemporal_store((f16)acc[i][j][r], Eb + (long)row * NN + colb);
      }
    }
  }

  // per-row softmax partials over this block's 128 cols (2 wave-columns)
#pragma unroll
  for (int i = 0; i < 4; ++i) {
#pragma unroll
    for (int r = 0; r < 4; ++r) {
      float m = fmaxf(fmaxf(acc[i][0][r], acc[i][1][r]),
                      fmaxf(acc[i][2][r], acc[i][3][r]));
#pragma unroll
      for (int s = 8; s >= 1; s >>= 1) m = fmaxf(m, __shfl_xor(m, s, 64));
      float sum = 0.f;
#pragma unroll
      for (int j = 0; j < 4; ++j) sum += __expf(acc[i][j][r] - m);
#pragma unroll
      for (int s = 8; s >= 1; s >>= 1) sum += __shfl_xor(sum, s, 64);
      if ((l & 15) == 0) {
        int Rl = wm + 16 * i + (l >> 4) * 4 + r;
        sm[Rl][wid & 1] = make_float2(m, sum);
      }
    }
  }
  __syncthreads();
  if (t < 256) {
    float2 a2 = sm[t][0], b2 = sm[t][1];
    float m = fmaxf(a2.x, b2.x);
    float s = a2.y * __expf(a2.x - m) + b2.y * __expf(b2.x - m);
    pstat[((long)bz * NN + row0 + t) * 32 + bx] = make_float2(m, s);
  }
}

// ---------------------------------------------------------------------------
// m97-structure NT GEMM (fallback path only).
// ---------------------------------------------------------------------------
template <int BIAS_MODE, int B_MODE, int OUT_MODE, bool GATE_EPI, bool SWZ>
__global__ __launch_bounds__(256) void gemm_nt_lds(
    const bf16* __restrict__ A, const void* __restrict__ Bm,
    const float* __restrict__ bias, void* __restrict__ D,
    const f16* __restrict__ gefl,
    int Ncols, int K, long sA, long sB, long sD, long sGe) {
  __shared__ bf16 As[128 * 32];
  __shared__ bf16 Bs[128 * 32];
  int bx = blockIdx.x, by = blockIdx.y, bz = blockIdx.z;
  if constexpr (SWZ) swz_bid(bx, by, bz);
  const bf16* Ab = A + (long)bz * sA;
  const f16* geb = GATE_EPI ? (gefl + bz * sGe) : nullptr;

  const int t   = threadIdx.x;
  const int wid = t >> 6;
  const int l   = t & 63;
  const int lr  = l & 15;
  const int lk  = (l >> 4) * 8;
  const int row0 = by * 128;
  const int col0 = bx * 128;
  const int warow = (wid >> 1) * 64;
  const int wbcol = (wid & 1) * 64;

  const int srow = t >> 2;
  const int scol = (t & 3) * 8;
  const int frow = t >> 3;
  const int fc4  = (t & 7) * 4;

  f32x4 acc[4][4];
#pragma unroll
  for (int i = 0; i < 4; ++i)
#pragma unroll
    for (int j = 0; j < 4; ++j) acc[i][j] = {0.f, 0.f, 0.f, 0.f};

  for (int k0 = 0; k0 < K; k0 += 32) {
    __syncthreads();
#pragma unroll
    for (int p = 0; p < 2; ++p)
      gload_lds16(Ab + (long)(row0 + srow + 64 * p) * K + k0 + scol,
                  As + ((p * 256 + t) * 8));
    if constexpr (B_MODE == 0) {
      const bf16* Bb = (const bf16*)Bm + (long)bz * sB;
#pragma unroll
      for (int p = 0; p < 2; ++p)
        gload_lds16(Bb + (long)(col0 + srow + 64 * p) * K + k0 + scol,
                    Bs + ((p * 256 + t) * 8));
    } else {
      const float* Bf = (const float*)Bm + (long)bz * sB;
#pragma unroll
      for (int p = 0; p < 4; ++p) {
        float4 u = *(const float4*)(Bf + (long)(col0 + frow + 32 * p) * K + k0 + fc4);
        bf16x4 tv;
        tv[0] = (bf16)u.x; tv[1] = (bf16)u.y; tv[2] = (bf16)u.z; tv[3] = (bf16)u.w;
        *(bf16x4*)(Bs + (frow + 32 * p) * 32 + fc4) = tv;
      }
    }
    __syncthreads();
    bf16x8 a[4], bb[4];
#pragma unroll
    for (int i = 0; i < 4; ++i)
      a[i] = *(const bf16x8*)(As + (warow + 16 * i + lr) * 32 + lk);
#pragma unroll
    for (int j = 0; j < 4; ++j)
      bb[j] = *(const bf16x8*)(Bs + (wbcol + 16 * j + lr) * 32 + lk);
#pragma unroll
    for (int i = 0; i < 4; ++i)
#pragma unroll
      for (int j = 0; j < 4; ++j)
        acc[i][j] = __builtin_amdgcn_mfma_f32_16x16x32_bf16(a[i], bb[j], acc[i][j], 0, 0, 0);
  }

  const int orow = (l >> 4) * 4;
  const int ocol = l & 15;
#pragma unroll
  for (int i = 0; i < 4; ++i) {
#pragma unroll
    for (int j = 0; j < 4; ++j) {
      int colb = col0 + wbcol + 16 * j + ocol;
#pragma unroll
      for (int r = 0; r < 4; ++r) {
        int row = row0 + warow + 16 * i + orow + r;
        float vv = acc[i][j][r];
        if constexpr (BIAS_MODE == 1) vv += bias[colb];
        if constexpr (BIAS_MODE == 2) vv += bias[row];
        if constexpr (GATE_EPI) {
          float g = (float)geb[(long)row * 4096 + colb];
          vv *= 1.f + 1.f / (1.f + __expf(-g));
        }
        long di = bz * sD + (long)row * Ncols + colb;
        if constexpr (OUT_MODE == 0)
          ((float*)D)[di] = vv;
        else if constexpr (OUT_MODE == 1)
          ((bf16*)D)[di] = (bf16)vv;
        else
          ((f16*)D)[di] = (f16)vv;
      }
    }
  }
}

// ---------------------------------------------------------------------------
// Fused rowstat+softmax+PV GEMM (r8 config + in-block stat reduce).
// BM=256 (all C), BN=64, BK=64, 8 waves, K-SPLIT x2. grid (64,2,B)=512 blocks.
// Prologue: each thread reduces its row's 32 pstat partials (4 local +
// 3-step shfl within its 8-lane group) -> {rowmax, 1/rowsum} in registers.
// V: global->register dbuf. P: fp16 E (nontemporal read) -> exp -> swizzled
// bf16 LDS (dbuf); ONE raw s_barrier + lgkmcnt per tile; nontemporal stores.
// ---------------------------------------------------------------------------
template <bool SWZ>
__global__ __launch_bounds__(512) void pv_fused_kernel(
    const bf16* __restrict__ V, const f16* __restrict__ E,
    const float2* __restrict__ pstat, float* __restrict__ attn,
    float* __restrict__ pbuf) {
  __shared__ bf16 Bs[2][64 * 64];   // P tile dbuf, chunk-swizzled
  int bx = blockIdx.x, by = blockIdx.y, bz = blockIdx.z;
  if constexpr (SWZ) swz_bid(bx, by, bz);
  const int mrow0 = bx * 64;
  const int KBASE = by * (NN / 2);
  const long NCst = (long)NN * CC;
  const long NNst = (long)NN * NN;
  const bf16* Vb = V + bz * NCst;
  const f16*  Eb = E + bz * NNst;
  float* attnb = attn + bz * NNst;
  float* pb = pbuf + (long)(bz * 2 + by) * NCst;

  const int t   = threadIdx.x;
  const int wid = t >> 6;         // 0..7 -> c rows [wid*32, +32)
  const int l   = t & 63;
  const int lr  = l & 15;
  const int lk8 = l >> 4;         // 0..3
  const int crow = wid * 32;

  // E/P mapping: rE = m row (0..63); q4 = col base; elems [q4,q4+4)+[q4+32,+4)
  const int rE = t >> 3;
  const int q4 = (t & 7) * 4;

  // in-block rowstat reduce: row rE, partials (t&7)*4 .. +3, then 8-lane merge
  float2 mi;
  {
    const float2* ps = pstat + ((long)bz * NN + mrow0 + rE) * 32 + (t & 7) * 4;
    float m = -1e30f, s = 0.f;
#pragma unroll
    for (int i = 0; i < 4; ++i) {
      float2 v = ps[i];
      float mn = fmaxf(m, v.x);
      s = s * __expf(m - mn) + v.y * __expf(v.x - mn);
      m = mn;
    }
#pragma unroll
    for (int msk = 1; msk <= 4; msk <<= 1) {
      float om = __shfl_xor(m, msk, 64);
      float os = __shfl_xor(s, msk, 64);
      float mn = fmaxf(m, om);
      s = s * __expf(m - mn) + os * __expf(om - mn);
      m = mn;
    }
    mi = make_float2(m, 1.f / s);
  }

  const f16* Erow = Eb + (long)(mrow0 + rE) * NN + q4;
  float* Arow = attnb + (long)(mrow0 + rE) * NN + q4;
  // swizzled LDS slots for the two bf16x4 half-chunks
  const int c8a = (t & 7) >> 1;
  const int o4  = (t & 1) * 4;
  const int woff1 = rE * 64 + ((c8a ^ (rE & 7)) << 3) + o4;
  const int woff2 = rE * 64 + (((c8a + 4) ^ (rE & 7)) << 3) + o4;

  // V fragment base pointers
  const bf16* Vr0 = Vb + (long)(crow + lr) * NN + lk8 * 8;
  const bf16* Vr1 = Vb + (long)(crow + 16 + lr) * NN + lk8 * 8;

  f32x4 acc[2][4];
#pragma unroll
  for (int i = 0; i < 2; ++i)
#pragma unroll
    for (int j = 0; j < 4; ++j) acc[i][j] = {0.f, 0.f, 0.f, 0.f};

  f16x4 elo = __builtin_nontemporal_load((const f16x4*)(Erow + KBASE));
  f16x4 ehi = __builtin_nontemporal_load((const f16x4*)(Erow + KBASE + 32));

  // produce P tile kdst into Bs[buf]; advances elo/ehi to tile kdst+64
  auto produce = [&](int kdst, int buf) {
    float pl[4], ph[4];
#pragma unroll
    for (int i = 0; i < 4; ++i) pl[i] = __expf((float)elo[i] - mi.x) * mi.y;
#pragma unroll
    for (int i = 0; i < 4; ++i) ph[i] = __expf((float)ehi[i] - mi.x) * mi.y;
    f32x4 u0 = {pl[0], pl[1], pl[2], pl[3]};
    f32x4 u1 = {ph[0], ph[1], ph[2], ph[3]};
    __builtin_nontemporal_store(u0, (f32x4*)(Arow + kdst));
    __builtin_nontemporal_store(u1, (f32x4*)(Arow + kdst + 32));
    bf16x4 b0, b1;
#pragma unroll
    for (int i = 0; i < 4; ++i) { b0[i] = (bf16)pl[i]; b1[i] = (bf16)ph[i]; }
    *(bf16x4*)(&Bs[buf][woff1]) = b0;
    *(bf16x4*)(&Bs[buf][woff2]) = b1;
    int kn = (kdst + 64) & (NN - 1);
    elo = __builtin_nontemporal_load((const f16x4*)(Erow + kn));
    ehi = __builtin_nontemporal_load((const f16x4*)(Erow + kn + 32));
  };

  auto consume = [&](int buf, bf16x8 a00, bf16x8 a01, bf16x8 a10, bf16x8 a11) {
    const bf16* B0 = &Bs[buf][0];
#pragma unroll
    for (int j = 0; j < 4; ++j) {
      int Rb = 16 * j + lr;
      bf16x8 b0 = *(const bf16x8*)(B0 + Rb * 64 + ((lk8 ^ (Rb & 7)) * 8));
      bf16x8 b1 = *(const bf16x8*)(B0 + Rb * 64 + (((lk8 + 4) ^ (Rb & 7)) * 8));
      acc[0][j] = __builtin_amdgcn_mfma_f32_16x16x32_bf16(a00, b0, acc[0][j], 0, 0, 0);
      acc[1][j] = __builtin_amdgcn_mfma_f32_16x16x32_bf16(a10, b0, acc[1][j], 0, 0, 0);
      acc[0][j] = __builtin_amdgcn_mfma_f32_16x16x32_bf16(a01, b1, acc[0][j], 0, 0, 0);
      acc[1][j] = __builtin_amdgcn_mfma_f32_16x16x32_bf16(a11, b1, acc[1][j], 0, 0, 0);
    }
  };

#define LOADV(k0, A0, A1, A2, A3)                  \
  A0 = *(const bf16x8*)(Vr0 + (k0));               \
  A1 = *(const bf16x8*)(Vr0 + (k0) + 32);          \
  A2 = *(const bf16x8*)(Vr1 + (k0));               \
  A3 = *(const bf16x8*)(Vr1 + (k0) + 32);

#define FENCE_BAR()                                         \
  asm volatile("s_waitcnt lgkmcnt(0)" ::: "memory");        \
  __builtin_amdgcn_s_barrier();                             \
  __builtin_amdgcn_sched_barrier(0);

  bf16x8 A00, A01, A10, A11, B00, B01, B10, B11;

  // prologue: tile 0 of this k-half
  produce(KBASE, 0);
  LOADV(KBASE, A00, A01, A10, A11);
  FENCE_BAR();

  for (int it = 0; it < 15; ++it) {
    int k0 = KBASE + it * 128;
    LOADV(k0 + 64, B00, B01, B10, B11);
    consume(0, A00, A01, A10, A11);
    produce(k0 + 64, 1);
    FENCE_BAR();
    LOADV(k0 + 128, A00, A01, A10, A11);
    consume(1, B00, B01, B10, B11);
    produce(k0 + 128, 0);
    FENCE_BAR();
  }
  // tile 30 (buf 0); prep tile 31
  LOADV(KBASE + 1984, B00, B01, B10, B11);
  consume(0, A00, A01, A10, A11);
  produce(KBASE + 1984, 1);
  FENCE_BAR();
  consume(1, B00, B01, B10, B11);
#undef LOADV
#undef FENCE_BAR

  // partial O store (no gate; combine kernel applies it)
  const int orow = (l >> 4) * 4;
  const int ocol = l & 15;
#pragma unroll
  for (int i = 0; i < 2; ++i) {
#pragma unroll
    for (int j = 0; j < 4; ++j) {
      int m = mrow0 + 16 * j + ocol;
#pragma unroll
      for (int r = 0; r < 4; ++r) {
        int c = crow + 16 * i + orow + r;
        __builtin_nontemporal_store(acc[i][j][r], pb + (long)c * 4096 + m);
      }
    }
  }
}

// ---------------------------------------------------------------------------
// combine: out = (p0 + p1) * (1 + sigmoid(ge)), flat over [B][C*N].
// ge (fp16) flat [N][C] memory reinterpreted as [C][W][H] (torch .view).
// ---------------------------------------------------------------------------
__global__ __launch_bounds__(256) void combine_kernel(
    const float* __restrict__ pbuf, const f16* __restrict__ ge,
    float* __restrict__ out) {
  const long NCst = (long)NN * CC;  // 2^20
  long i = ((long)blockIdx.x * 256 + threadIdx.x) * 8;
  int b = (int)(i >> 20);
  long r = i & (NCst - 1);
  const float* p0 = pbuf + (long)(b * 2) * NCst + r;
  const float* p1 = p0 + NCst;
  const f16* g = ge + (long)b * NCst + r;
  float* o = out + i;
  f16x8 gv = *(const f16x8*)(g);
#pragma unroll
  for (int h = 0; h < 2; ++h) {
    float4 a = *(const float4*)(p0 + h * 4);
    float4 c = *(const float4*)(p1 + h * 4);
    float4 u;
    u.x = (a.x + c.x) * (1.f + 1.f / (1.f + __expf(-(float)gv[4 * h + 0])));
    u.y = (a.y + c.y) * (1.f + 1.f / (1.f + __expf(-(float)gv[4 * h + 1])));
    u.z = (a.z + c.z) * (1.f + 1.f / (1.f + __expf(-(float)gv[4 * h + 2])));
    u.w = (a.w + c.w) * (1.f + 1.f / (1.f + __expf(-(float)gv[4 * h + 3])));
    *(float4*)(o + h * 4) = u;
  }
}

// ---------------------------------------------------------------------------
// gate: per row n: s = <q,Wgg[0:256]> + <ge,Wgg[256:512]> + bgg;
//       q += sigmoid(s)*ge. One wave per row. ge fp16.
// ---------------------------------------------------------------------------
__global__ __launch_bounds__(256) void gate_kernel(
    bf16* __restrict__ q, const f16* __restrict__ ge,
    const float* __restrict__ Wgg, const float* __restrict__ bgg) {
  int row = blockIdx.x * 4 + (threadIdx.x >> 6);
  int l = threadIdx.x & 63;
  bf16* qr = q + (long)row * 256;
  const f16* ger = ge + (long)row * 256;
  float s = 0.f;
  float qv[4], gv[4];
#pragma unroll
  for (int i = 0; i < 4; ++i) {
    int o = l + 64 * i;
    qv[i] = (float)qr[o];
    gv[i] = (float)ger[o];
    s += qv[i] * Wgg[o] + gv[i] * Wgg[256 + o];
  }
#pragma unroll
  for (int m = 32; m >= 1; m >>= 1) s += __shfl_xor(s, m, 64);
  float gate = 1.f / (1.f + __expf(-(s + bgg[0])));
#pragma unroll
  for (int i = 0; i < 4; ++i) {
    int o = l + 64 * i;
    qr[o] = (bf16)(qv[i] + gate * gv[i]);
  }
}

// ---------------------------------------------------------------------------
// fallback fp32 softmax (small-ws path)
// ---------------------------------------------------------------------------
__global__ __launch_bounds__(256) void softmax32_kernel(float* __restrict__ attn) {
  long row = blockIdx.x;
  float* p = attn + row * 4096;
  int t = threadIdx.x;
  __shared__ float red[8];
  float4 v[4];
  float mx = -1e30f;
#pragma unroll
  for (int c = 0; c < 4; ++c) {
    v[c] = *(const float4*)(p + c * 1024 + t * 4);
    mx = fmaxf(mx, fmaxf(fmaxf(v[c].x, v[c].y), fmaxf(v[c].z, v[c].w)));
  }
#pragma unroll
  for (int m = 32; m >= 1; m >>= 1) mx = fmaxf(mx, __shfl_xor(mx, m, 64));
  if ((t & 63) == 0) red[t >> 6] = mx;
  __syncthreads();
  mx = fmaxf(fmaxf(red[0], red[1]), fmaxf(red[2], red[3]));
  float sum = 0.f;
#pragma unroll
  for (int c = 0; c < 4; ++c) {
    v[c].x = __expf(v[c].x - mx);
    v[c].y = __expf(v[c].y - mx);
    v[c].z = __expf(v[c].z - mx);
    v[c].w = __expf(v[c].w - mx);
    sum += v[c].x + v[c].y + v[c].z + v[c].w;
  }
#pragma unroll
  for (int m = 32; m >= 1; m >>= 1) sum += __shfl_xor(sum, m, 64);
  if ((t & 63) == 0) red[4 + (t >> 6)] = sum;
  __syncthreads();
  float inv = 1.f / (red[4] + red[5] + red[6] + red[7]);
#pragma unroll
  for (int c = 0; c < 4; ++c) {
    v[c].x *= inv; v[c].y *= inv; v[c].z *= inv; v[c].w *= inv;
    *(float4*)(p + c * 1024 + t * 4) = v[c];
  }
}

// ---------------------------------------------------------------------------
extern "C" void kernel_launch(void* const* d_in, const int* in_sizes, int n_in,
                              void* d_out, int out_size, void* d_ws, size_t ws_size,
                              hipStream_t stream) {
  const float* x    = (const float*)d_in[0];
  const float* geo  = (const float*)d_in[1];
  const float* Wq   = (const float*)d_in[2];
  const float* bq   = (const float*)d_in[3];
  const float* Wk   = (const float*)d_in[4];
  const float* bk   = (const float*)d_in[5];
  const float* Wv   = (const float*)d_in[6];
  const float* bv   = (const float*)d_in[7];
  const float* Wgp  = (const float*)d_in[8];
  const float* bgp  = (const float*)d_in[9];
  const float* Wgg  = (const float*)d_in[10];
  const float* bgg  = (const float*)d_in[11];

  float* out  = (float*)d_out;                    // [B][C][N]
  float* attn = out + (long)BB * CC * NN;         // [B][N][N]

  char* w = (char*)d_ws;
  size_t used = 0;
  auto alloc = [&](size_t bytes) {
    char* p = w + used;
    used += (bytes + 255) & ~(size_t)255;
    return p;
  };
  bf16*  xt   = (bf16*)alloc((size_t)BB * NN * CC * 2);  // [B][N][C]
  bf16*  qn   = (bf16*)alloc((size_t)BB * NN * CC * 2);  // [B][N][O]
  bf16*  kn   = (bf16*)alloc((size_t)BB * NN * CC * 2);  // [B][N][O]
  bf16*  vb   = (bf16*)alloc((size_t)BB * CC * NN * 2);  // [B][O][N]
  f16*   ge   = (f16*)alloc((size_t)BB * NN * CC * 2);   // [B][N][O] fp16
  bf16*  Wall = (bf16*)alloc((size_t)4 * CC * CC * 2);
  // fp16 energy (134MB) + stats + k-split partials — only if ws allows
  size_t abf_bytes   = (size_t)BB * NN * NN * 2;
  size_t pstat_bytes = (size_t)BB * NN * 32 * sizeof(float2);
  size_t pbuf_bytes  = (size_t)BB * 2 * NN * CC * 4;     // 33.5MB
  bool big = (ws_size >= used + abf_bytes + pstat_bytes + pbuf_bytes + 2048);
  f16* abf = nullptr;
  float2* pstat = nullptr;
  float* pbuf = nullptr;
  if (big) {
    abf   = (f16*)alloc(abf_bytes);
    pstat = (float2*)alloc(pstat_bytes);
    pbuf  = (float*)alloc(pbuf_bytes);
  }

  const long NCst = (long)NN * CC;  // 1,048,576
  const long NNst = (long)NN * NN;  // 16,777,216

  // converts + transpose
  cvt_weights_kernel<<<dim3(64, 4), 256, 0, stream>>>(Wq, Wk, Wv, Wgp, Wall);
  transpose_x_kernel<<<dim3(4, 64, BB), 256, 0, stream>>>(x, xt);

  // fused projections: q, ge (direct fp32 geo -> fp16 ge), k, v
  proj_all_kernel<<<dim3(2, 32, BB * 4), 256, 0, stream>>>(
      xt, geo, Wall, bq, bgp, bk, bv, qn, ge, kn, vb);
  // gate update on qn
  gate_kernel<<<(BB * NN) / 4, 256, 0, stream>>>(qn, ge, Wgg, bgg);

  if (big) {
    // energy = qn . kn^T -> fp16 (nt) + softmax partials
    energy_kernel<true><<<dim3(32, 16, BB), 512, 0, stream>>>(
        qn, kn, abf, pstat);
    // fused rowstat + softmax + PV (r8 config, nt streams)
    pv_fused_kernel<true><<<dim3(64, 2, BB), 512, 0, stream>>>(
        vb, abf, pstat, attn, pbuf);
    // combine partials + gate epilogue
    combine_kernel<<<(int)((long)BB * NCst / (256 * 8)), 256, 0, stream>>>(
        pbuf, ge, out);
  } else {
    gemm_nt_lds<0, 0, 0, false, true><<<dim3(32, 32, BB), 256, 0, stream>>>(
        qn, kn, nullptr, attn, nullptr, NN, CC, NCst, NCst, NNst, 0);
    softmax32_kernel<<<BB * NN, 256, 0, stream>>>(attn);
    gemm_nt_lds<0, 1, 0, true, true><<<dim3(32, 2, BB), 256, 0, stream>>>(
        vb, attn, nullptr, out, ge, NN, NN, NCst, NNst, NCst, NCst);
  }
}

// Round 15
// 252.667 us; speedup vs baseline: 1.2263x; 1.2263x over previous
//
#include <hip/hip_runtime.h>
#include <hip/hip_bf16.h>
#include <math.h>

// Problem constants
static constexpr int BB = 4;     // batch
static constexpr int CC = 256;   // channels
static constexpr int NN = 4096;  // pixels (64*64)

using bf16   = __bf16;
using f16    = _Float16;
using bf16x8 = __attribute__((ext_vector_type(8))) __bf16;
using bf16x4 = __attribute__((ext_vector_type(4))) __bf16;
using f16x8  = __attribute__((ext_vector_type(8))) _Float16;
using f16x4  = __attribute__((ext_vector_type(4))) _Float16;
using f32x4  = __attribute__((ext_vector_type(4))) float;

// async global->LDS, 16B per lane (dest must be wave-uniform base + lane*16)
__device__ inline void gload_lds16(const void* g, void* l) {
  __builtin_amdgcn_global_load_lds(
      (const __attribute__((address_space(1))) void*)g,
      (__attribute__((address_space(3))) void*)l, 16, 0, 0);
}

// XCD-aware bijective block remap (requires nwg % 8 == 0; all call sites OK).
__device__ inline void swz_bid(int& xb, int& yb, int& zb) {
  int gx = gridDim.x, gy = gridDim.y;
  int nwg = gx * gy * (int)gridDim.z;
  int flat = blockIdx.x + gx * (blockIdx.y + gy * blockIdx.z);
  int q = nwg >> 3;
  int w = (flat & 7) * q + (flat >> 3);
  xb = w % gx;
  int r = w / gx;
  yb = r % gy;
  zb = r / gy;
}

// ---------------------------------------------------------------------------
// all four weight matrices fp32 -> bf16 in one launch. grid (64, 4)
// ---------------------------------------------------------------------------
__global__ __launch_bounds__(256) void cvt_weights_kernel(
    const float* __restrict__ w0, const float* __restrict__ w1,
    const float* __restrict__ w2, const float* __restrict__ w3,
    bf16* __restrict__ out) {
  const float* srcs[4] = {w0, w1, w2, w3};
  const float* s = srcs[blockIdx.y];
  bf16* dst = out + (size_t)blockIdx.y * (CC * CC);
  int i = (blockIdx.x * 256 + threadIdx.x) * 4;
  float4 v = *(const float4*)(s + i);
  bf16x4 t;
  t[0] = (bf16)v.x; t[1] = (bf16)v.y; t[2] = (bf16)v.z; t[3] = (bf16)v.w;
  *(bf16x4*)(dst + i) = t;
}

// ---------------------------------------------------------------------------
// transpose x [B][C][N] fp32 -> xt [B][N][C] bf16
// ---------------------------------------------------------------------------
__global__ __launch_bounds__(256) void transpose_x_kernel(
    const float* __restrict__ x, bf16* __restrict__ xt) {
  __shared__ float tile[64][65];
  int b  = blockIdx.z;
  int c0 = blockIdx.x * 64;
  int n0 = blockIdx.y * 64;
  const float* xp = x  + (long)b * CC * NN;
  bf16*       xtp = xt + (long)b * NN * CC;
  int tj = threadIdx.x & 63;
  int ti = threadIdx.x >> 6;
#pragma unroll
  for (int p = 0; p < 16; ++p) {
    int i = ti + p * 4;
    tile[i][tj] = xp[(long)(c0 + i) * NN + n0 + tj];
  }
  __syncthreads();
#pragma unroll
  for (int p = 0; p < 16; ++p) {
    int i = ti + p * 4;
    xtp[(long)(n0 + i) * CC + c0 + tj] = (bf16)tile[tj][i];
  }
}

// ---------------------------------------------------------------------------
// Fused 4-projection GEMM. blockIdx.z = b*4 + p, p in {0:q,1:ge,2:k,3:v}.
// p==1 reads geo (fp32) directly with reg-staged convert; ge written fp16.
// ---------------------------------------------------------------------------
__global__ __launch_bounds__(256) void proj_all_kernel(
    const bf16* __restrict__ xt, const float* __restrict__ geo,
    const bf16* __restrict__ Wall,
    const float* __restrict__ bq, const float* __restrict__ bgp,
    const float* __restrict__ bk, const float* __restrict__ bv,
    bf16* __restrict__ qn, f16* __restrict__ ge,
    bf16* __restrict__ kn, bf16* __restrict__ vb) {
  __shared__ bf16 As[128 * 32];
  __shared__ bf16 Bs[128 * 32];
  const long NCst = (long)NN * CC;
  const int bz = blockIdx.z;
  const int b = bz >> 2, p = bz & 3;
  const bf16 *Ap = nullptr, *Bp;
  const float* Af32 = nullptr;
  const float* bias;
  int row0, col0;
  if (p == 3) {
    Ap = Wall + 2 * CC * CC;        // Wv
    Bp = xt + b * NCst;
    bias = bv;
    row0 = blockIdx.x * 128;        // M=256
    col0 = blockIdx.y * 128;        // N=4096
  } else {
    if (p == 1) Af32 = geo + b * NCst;
    else        Ap   = xt + b * NCst;
    Bp = Wall + (size_t)(p == 0 ? 0 : (p == 1 ? 3 : 1)) * CC * CC;
    bias = (p == 0 ? bq : (p == 1 ? bgp : bk));
    row0 = blockIdx.y * 128;
    col0 = blockIdx.x * 128;
  }

  const int t   = threadIdx.x;
  const int wid = t >> 6;
  const int l   = t & 63;
  const int lr  = l & 15;
  const int lk  = (l >> 4) * 8;
  const int warow = (wid >> 1) * 64;
  const int wbcol = (wid & 1) * 64;
  const int srow = t >> 2;
  const int scol = (t & 3) * 8;
  const int frow = t >> 3;        // fp32 A staging (p==1)
  const int fc4  = (t & 7) * 4;

  f32x4 acc[4][4];
#pragma unroll
  for (int i = 0; i < 4; ++i)
#pragma unroll
    for (int j = 0; j < 4; ++j) acc[i][j] = {0.f, 0.f, 0.f, 0.f};

  for (int k0 = 0; k0 < CC; k0 += 32) {
    __syncthreads();
    if (p == 1) {
#pragma unroll
      for (int q = 0; q < 4; ++q) {
        float4 u = *(const float4*)(Af32 + (long)(row0 + frow + 32 * q) * CC + k0 + fc4);
        bf16x4 tv;
        tv[0] = (bf16)u.x; tv[1] = (bf16)u.y; tv[2] = (bf16)u.z; tv[3] = (bf16)u.w;
        *(bf16x4*)(As + (frow + 32 * q) * 32 + fc4) = tv;
      }
    } else {
#pragma unroll
      for (int q = 0; q < 2; ++q)
        gload_lds16(Ap + (long)(row0 + srow + 64 * q) * CC + k0 + scol,
                    As + ((q * 256 + t) * 8));
    }
#pragma unroll
    for (int q = 0; q < 2; ++q)
      gload_lds16(Bp + (long)(col0 + srow + 64 * q) * CC + k0 + scol,
                  Bs + ((q * 256 + t) * 8));
    __syncthreads();
    bf16x8 a[4], bb[4];
#pragma unroll
    for (int i = 0; i < 4; ++i)
      a[i] = *(const bf16x8*)(As + (warow + 16 * i + lr) * 32 + lk);
#pragma unroll
    for (int j = 0; j < 4; ++j)
      bb[j] = *(const bf16x8*)(Bs + (wbcol + 16 * j + lr) * 32 + lk);
#pragma unroll
    for (int i = 0; i < 4; ++i)
#pragma unroll
      for (int j = 0; j < 4; ++j)
        acc[i][j] = __builtin_amdgcn_mfma_f32_16x16x32_bf16(a[i], bb[j], acc[i][j], 0, 0, 0);
  }

  const int orow = (l >> 4) * 4;
  const int ocol = l & 15;
#pragma unroll
  for (int i = 0; i < 4; ++i) {
#pragma unroll
    for (int j = 0; j < 4; ++j) {
      int colb = col0 + wbcol + 16 * j + ocol;
#pragma unroll
      for (int r = 0; r < 4; ++r) {
        int row = row0 + warow + 16 * i + orow + r;
        if (p == 3) {
          float vv = acc[i][j][r] + bias[row];
          vb[b * NCst + (long)row * NN + colb] = (bf16)vv;
        } else {
          float vv = acc[i][j][r] + bias[colb];
          long di = b * NCst + (long)row * CC + colb;
          if (p == 1)
            ge[di] = (f16)vv;
          else
            (p == 0 ? qn : kn)[di] = (bf16)vv;
        }
      }
    }
  }
}

// ---------------------------------------------------------------------------
// Energy GEMM: E[r][c] = sum_k q[r][k]*kn[c][k], fp16 out (NORMAL stores —
// nontemporal 2B scalar stores caused write amplification in r14) +
// per-row/128-col softmax partials. 256x128 tile, 8 waves, BK=64, chunk-XOR
// swizzled LDS. grid (32, 16, B).
// ---------------------------------------------------------------------------
template <bool SWZ>
__global__ __launch_bounds__(512) void energy_kernel(
    const bf16* __restrict__ Q, const bf16* __restrict__ K,
    f16* __restrict__ E, float2* __restrict__ pstat) {
  __shared__ bf16 As[256 * 64];     // 32 KB
  __shared__ bf16 Bs[128 * 64];     // 16 KB
  __shared__ float2 sm[256][2];     // 4 KB
  int bx = blockIdx.x, by = blockIdx.y, bz = blockIdx.z;
  if constexpr (SWZ) swz_bid(bx, by, bz);
  const long NCst = (long)NN * CC;
  const long NNst = (long)NN * NN;
  const bf16* Qb = Q + bz * NCst;
  const bf16* Kb = K + bz * NCst;
  f16* Eb = E + bz * NNst;
  const int row0 = by * 256;
  const int col0 = bx * 128;

  const int t   = threadIdx.x;
  const int wid = t >> 6;
  const int l   = t & 63;
  const int lr  = l & 15;
  const int lk8 = l >> 4;           // 0..3
  const int wm  = (wid >> 1) * 64;  // wave M offset (0..192)
  const int wn  = (wid & 1) * 64;   // wave N offset (0/64)

  const int srow = t >> 3;          // 0..63 (staging local row)
  const int schk = t & 7;           // staging chunk

  f32x4 acc[4][4];
#pragma unroll
  for (int i = 0; i < 4; ++i)
#pragma unroll
    for (int j = 0; j < 4; ++j) acc[i][j] = {0.f, 0.f, 0.f, 0.f};

  for (int k0 = 0; k0 < CC; k0 += 64) {
    __syncthreads();
#pragma unroll
    for (int p = 0; p < 4; ++p) {
      int r = srow + 64 * p;
      gload_lds16(Qb + (long)(row0 + r) * CC + k0 + ((schk ^ (r & 7)) * 8),
                  As + ((p * 512 + t) * 8));
    }
#pragma unroll
    for (int p = 0; p < 2; ++p) {
      int r = srow + 64 * p;
      gload_lds16(Kb + (long)(col0 + r) * CC + k0 + ((schk ^ (r & 7)) * 8),
                  Bs + ((p * 512 + t) * 8));
    }
    __syncthreads();
#pragma unroll
    for (int kk = 0; kk < 2; ++kk) {
      bf16x8 a[4], b[4];
#pragma unroll
      for (int i = 0; i < 4; ++i) {
        int Ra = wm + 16 * i + lr;
        a[i] = *(const bf16x8*)(As + Ra * 64 + (((kk * 4 + lk8) ^ (Ra & 7)) * 8));
      }
#pragma unroll
      for (int j = 0; j < 4; ++j) {
        int Rb = wn + 16 * j + lr;
        b[j] = *(const bf16x8*)(Bs + Rb * 64 + (((kk * 4 + lk8) ^ (Rb & 7)) * 8));
      }
#pragma unroll
      for (int i = 0; i < 4; ++i)
#pragma unroll
        for (int j = 0; j < 4; ++j)
          acc[i][j] = __builtin_amdgcn_mfma_f32_16x16x32_bf16(a[i], b[j], acc[i][j], 0, 0, 0);
    }
  }

  const int orow = (l >> 4) * 4;
  const int ocol = l & 15;
#pragma unroll
  for (int i = 0; i < 4; ++i) {
#pragma unroll
    for (int j = 0; j < 4; ++j) {
      int colb = col0 + wn + 16 * j + ocol;
#pragma unroll
      for (int r = 0; r < 4; ++r) {
        int row = row0 + wm + 16 * i + orow + r;
        Eb[(long)row * NN + colb] = (f16)acc[i][j][r];
      }
    }
  }

  // per-row softmax partials over this block's 128 cols (2 wave-columns)
#pragma unroll
  for (int i = 0; i < 4; ++i) {
#pragma unroll
    for (int r = 0; r < 4; ++r) {
      float m = fmaxf(fmaxf(acc[i][0][r], acc[i][1][r]),
                      fmaxf(acc[i][2][r], acc[i][3][r]));
#pragma unroll
      for (int s = 8; s >= 1; s >>= 1) m = fmaxf(m, __shfl_xor(m, s, 64));
      float sum = 0.f;
#pragma unroll
      for (int j = 0; j < 4; ++j) sum += __expf(acc[i][j][r] - m);
#pragma unroll
      for (int s = 8; s >= 1; s >>= 1) sum += __shfl_xor(sum, s, 64);
      if ((l & 15) == 0) {
        int Rl = wm + 16 * i + (l >> 4) * 4 + r;
        sm[Rl][wid & 1] = make_float2(m, sum);
      }
    }
  }
  __syncthreads();
  if (t < 256) {
    float2 a2 = sm[t][0], b2 = sm[t][1];
    float m = fmaxf(a2.x, b2.x);
    float s = a2.y * __expf(a2.x - m) + b2.y * __expf(b2.x - m);
    pstat[((long)bz * NN + row0 + t) * 32 + bx] = make_float2(m, s);
  }
}

// ---------------------------------------------------------------------------
// m97-structure NT GEMM (fallback path only).
// ---------------------------------------------------------------------------
template <int BIAS_MODE, int B_MODE, int OUT_MODE, bool GATE_EPI, bool SWZ>
__global__ __launch_bounds__(256) void gemm_nt_lds(
    const bf16* __restrict__ A, const void* __restrict__ Bm,
    const float* __restrict__ bias, void* __restrict__ D,
    const f16* __restrict__ gefl,
    int Ncols, int K, long sA, long sB, long sD, long sGe) {
  __shared__ bf16 As[128 * 32];
  __shared__ bf16 Bs[128 * 32];
  int bx = blockIdx.x, by = blockIdx.y, bz = blockIdx.z;
  if constexpr (SWZ) swz_bid(bx, by, bz);
  const bf16* Ab = A + (long)bz * sA;
  const f16* geb = GATE_EPI ? (gefl + bz * sGe) : nullptr;

  const int t   = threadIdx.x;
  const int wid = t >> 6;
  const int l   = t & 63;
  const int lr  = l & 15;
  const int lk  = (l >> 4) * 8;
  const int row0 = by * 128;
  const int col0 = bx * 128;
  const int warow = (wid >> 1) * 64;
  const int wbcol = (wid & 1) * 64;

  const int srow = t >> 2;
  const int scol = (t & 3) * 8;
  const int frow = t >> 3;
  const int fc4  = (t & 7) * 4;

  f32x4 acc[4][4];
#pragma unroll
  for (int i = 0; i < 4; ++i)
#pragma unroll
    for (int j = 0; j < 4; ++j) acc[i][j] = {0.f, 0.f, 0.f, 0.f};

  for (int k0 = 0; k0 < K; k0 += 32) {
    __syncthreads();
#pragma unroll
    for (int p = 0; p < 2; ++p)
      gload_lds16(Ab + (long)(row0 + srow + 64 * p) * K + k0 + scol,
                  As + ((p * 256 + t) * 8));
    if constexpr (B_MODE == 0) {
      const bf16* Bb = (const bf16*)Bm + (long)bz * sB;
#pragma unroll
      for (int p = 0; p < 2; ++p)
        gload_lds16(Bb + (long)(col0 + srow + 64 * p) * K + k0 + scol,
                    Bs + ((p * 256 + t) * 8));
    } else {
      const float* Bf = (const float*)Bm + (long)bz * sB;
#pragma unroll
      for (int p = 0; p < 4; ++p) {
        float4 u = *(const float4*)(Bf + (long)(col0 + frow + 32 * p) * K + k0 + fc4);
        bf16x4 tv;
        tv[0] = (bf16)u.x; tv[1] = (bf16)u.y; tv[2] = (bf16)u.z; tv[3] = (bf16)u.w;
        *(bf16x4*)(Bs + (frow + 32 * p) * 32 + fc4) = tv;
      }
    }
    __syncthreads();
    bf16x8 a[4], bb[4];
#pragma unroll
    for (int i = 0; i < 4; ++i)
      a[i] = *(const bf16x8*)(As + (warow + 16 * i + lr) * 32 + lk);
#pragma unroll
    for (int j = 0; j < 4; ++j)
      bb[j] = *(const bf16x8*)(Bs + (wbcol + 16 * j + lr) * 32 + lk);
#pragma unroll
    for (int i = 0; i < 4; ++i)
#pragma unroll
      for (int j = 0; j < 4; ++j)
        acc[i][j] = __builtin_amdgcn_mfma_f32_16x16x32_bf16(a[i], bb[j], acc[i][j], 0, 0, 0);
  }

  const int orow = (l >> 4) * 4;
  const int ocol = l & 15;
#pragma unroll
  for (int i = 0; i < 4; ++i) {
#pragma unroll
    for (int j = 0; j < 4; ++j) {
      int colb = col0 + wbcol + 16 * j + ocol;
#pragma unroll
      for (int r = 0; r < 4; ++r) {
        int row = row0 + warow + 16 * i + orow + r;
        float vv = acc[i][j][r];
        if constexpr (BIAS_MODE == 1) vv += bias[colb];
        if constexpr (BIAS_MODE == 2) vv += bias[row];
        if constexpr (GATE_EPI) {
          float g = (float)geb[(long)row * 4096 + colb];
          vv *= 1.f + 1.f / (1.f + __expf(-g));
        }
        long di = bz * sD + (long)row * Ncols + colb;
        if constexpr (OUT_MODE == 0)
          ((float*)D)[di] = vv;
        else if constexpr (OUT_MODE == 1)
          ((bf16*)D)[di] = (bf16)vv;
        else
          ((f16*)D)[di] = (f16)vv;
      }
    }
  }
}

// ---------------------------------------------------------------------------
// Fused rowstat+softmax+PV GEMM (r8 config + in-block stat reduce).
// BM=256 (all C), BN=64, BK=64, 8 waves, K-SPLIT x2. grid (64,2,B)=512 blocks.
// Prologue: each thread reduces its row's 32 pstat partials (4 local +
// 3-step shfl within its 8-lane group) -> {rowmax, 1/rowsum} in registers.
// V: global->register dbuf. P: fp16 E (normal loads) -> exp -> swizzled
// bf16 LDS (dbuf); ONE raw s_barrier + lgkmcnt per tile; nontemporal
// attn (16B) / pbuf stores only.
// ---------------------------------------------------------------------------
template <bool SWZ>
__global__ __launch_bounds__(512) void pv_fused_kernel(
    const bf16* __restrict__ V, const f16* __restrict__ E,
    const float2* __restrict__ pstat, float* __restrict__ attn,
    float* __restrict__ pbuf) {
  __shared__ bf16 Bs[2][64 * 64];   // P tile dbuf, chunk-swizzled
  int bx = blockIdx.x, by = blockIdx.y, bz = blockIdx.z;
  if constexpr (SWZ) swz_bid(bx, by, bz);
  const int mrow0 = bx * 64;
  const int KBASE = by * (NN / 2);
  const long NCst = (long)NN * CC;
  const long NNst = (long)NN * NN;
  const bf16* Vb = V + bz * NCst;
  const f16*  Eb = E + bz * NNst;
  float* attnb = attn + bz * NNst;
  float* pb = pbuf + (long)(bz * 2 + by) * NCst;

  const int t   = threadIdx.x;
  const int wid = t >> 6;         // 0..7 -> c rows [wid*32, +32)
  const int l   = t & 63;
  const int lr  = l & 15;
  const int lk8 = l >> 4;         // 0..3
  const int crow = wid * 32;

  // E/P mapping: rE = m row (0..63); q4 = col base; elems [q4,q4+4)+[q4+32,+4)
  const int rE = t >> 3;
  const int q4 = (t & 7) * 4;

  // in-block rowstat reduce: row rE, partials (t&7)*4 .. +3, then 8-lane merge
  float2 mi;
  {
    const float2* ps = pstat + ((long)bz * NN + mrow0 + rE) * 32 + (t & 7) * 4;
    float m = -1e30f, s = 0.f;
#pragma unroll
    for (int i = 0; i < 4; ++i) {
      float2 v = ps[i];
      float mn = fmaxf(m, v.x);
      s = s * __expf(m - mn) + v.y * __expf(v.x - mn);
      m = mn;
    }
#pragma unroll
    for (int msk = 1; msk <= 4; msk <<= 1) {
      float om = __shfl_xor(m, msk, 64);
      float os = __shfl_xor(s, msk, 64);
      float mn = fmaxf(m, om);
      s = s * __expf(m - mn) + os * __expf(om - mn);
      m = mn;
    }
    mi = make_float2(m, 1.f / s);
  }

  const f16* Erow = Eb + (long)(mrow0 + rE) * NN + q4;
  float* Arow = attnb + (long)(mrow0 + rE) * NN + q4;
  // swizzled LDS slots for the two bf16x4 half-chunks
  const int c8a = (t & 7) >> 1;
  const int o4  = (t & 1) * 4;
  const int woff1 = rE * 64 + ((c8a ^ (rE & 7)) << 3) + o4;
  const int woff2 = rE * 64 + (((c8a + 4) ^ (rE & 7)) << 3) + o4;

  // V fragment base pointers
  const bf16* Vr0 = Vb + (long)(crow + lr) * NN + lk8 * 8;
  const bf16* Vr1 = Vb + (long)(crow + 16 + lr) * NN + lk8 * 8;

  f32x4 acc[2][4];
#pragma unroll
  for (int i = 0; i < 2; ++i)
#pragma unroll
    for (int j = 0; j < 4; ++j) acc[i][j] = {0.f, 0.f, 0.f, 0.f};

  f16x4 elo = *(const f16x4*)(Erow + KBASE);
  f16x4 ehi = *(const f16x4*)(Erow + KBASE + 32);

  // produce P tile kdst into Bs[buf]; advances elo/ehi to tile kdst+64
  auto produce = [&](int kdst, int buf) {
    float pl[4], ph[4];
#pragma unroll
    for (int i = 0; i < 4; ++i) pl[i] = __expf((float)elo[i] - mi.x) * mi.y;
#pragma unroll
    for (int i = 0; i < 4; ++i) ph[i] = __expf((float)ehi[i] - mi.x) * mi.y;
    f32x4 u0 = {pl[0], pl[1], pl[2], pl[3]};
    f32x4 u1 = {ph[0], ph[1], ph[2], ph[3]};
    __builtin_nontemporal_store(u0, (f32x4*)(Arow + kdst));
    __builtin_nontemporal_store(u1, (f32x4*)(Arow + kdst + 32));
    bf16x4 b0, b1;
#pragma unroll
    for (int i = 0; i < 4; ++i) { b0[i] = (bf16)pl[i]; b1[i] = (bf16)ph[i]; }
    *(bf16x4*)(&Bs[buf][woff1]) = b0;
    *(bf16x4*)(&Bs[buf][woff2]) = b1;
    int kn = (kdst + 64) & (NN - 1);
    elo = *(const f16x4*)(Erow + kn);
    ehi = *(const f16x4*)(Erow + kn + 32);
  };

  auto consume = [&](int buf, bf16x8 a00, bf16x8 a01, bf16x8 a10, bf16x8 a11) {
    const bf16* B0 = &Bs[buf][0];
#pragma unroll
    for (int j = 0; j < 4; ++j) {
      int Rb = 16 * j + lr;
      bf16x8 b0 = *(const bf16x8*)(B0 + Rb * 64 + ((lk8 ^ (Rb & 7)) * 8));
      bf16x8 b1 = *(const bf16x8*)(B0 + Rb * 64 + (((lk8 + 4) ^ (Rb & 7)) * 8));
      acc[0][j] = __builtin_amdgcn_mfma_f32_16x16x32_bf16(a00, b0, acc[0][j], 0, 0, 0);
      acc[1][j] = __builtin_amdgcn_mfma_f32_16x16x32_bf16(a10, b0, acc[1][j], 0, 0, 0);
      acc[0][j] = __builtin_amdgcn_mfma_f32_16x16x32_bf16(a01, b1, acc[0][j], 0, 0, 0);
      acc[1][j] = __builtin_amdgcn_mfma_f32_16x16x32_bf16(a11, b1, acc[1][j], 0, 0, 0);
    }
  };

#define LOADV(k0, A0, A1, A2, A3)                  \
  A0 = *(const bf16x8*)(Vr0 + (k0));               \
  A1 = *(const bf16x8*)(Vr0 + (k0) + 32);          \
  A2 = *(const bf16x8*)(Vr1 + (k0));               \
  A3 = *(const bf16x8*)(Vr1 + (k0) + 32);

#define FENCE_BAR()                                         \
  asm volatile("s_waitcnt lgkmcnt(0)" ::: "memory");        \
  __builtin_amdgcn_s_barrier();                             \
  __builtin_amdgcn_sched_barrier(0);

  bf16x8 A00, A01, A10, A11, B00, B01, B10, B11;

  // prologue: tile 0 of this k-half
  produce(KBASE, 0);
  LOADV(KBASE, A00, A01, A10, A11);
  FENCE_BAR();

  for (int it = 0; it < 15; ++it) {
    int k0 = KBASE + it * 128;
    LOADV(k0 + 64, B00, B01, B10, B11);
    consume(0, A00, A01, A10, A11);
    produce(k0 + 64, 1);
    FENCE_BAR();
    LOADV(k0 + 128, A00, A01, A10, A11);
    consume(1, B00, B01, B10, B11);
    produce(k0 + 128, 0);
    FENCE_BAR();
  }
  // tile 30 (buf 0); prep tile 31
  LOADV(KBASE + 1984, B00, B01, B10, B11);
  consume(0, A00, A01, A10, A11);
  produce(KBASE + 1984, 1);
  FENCE_BAR();
  consume(1, B00, B01, B10, B11);
#undef LOADV
#undef FENCE_BAR

  // partial O store (no gate; combine kernel applies it)
  const int orow = (l >> 4) * 4;
  const int ocol = l & 15;
#pragma unroll
  for (int i = 0; i < 2; ++i) {
#pragma unroll
    for (int j = 0; j < 4; ++j) {
      int m = mrow0 + 16 * j + ocol;
#pragma unroll
      for (int r = 0; r < 4; ++r) {
        int c = crow + 16 * i + orow + r;
        __builtin_nontemporal_store(acc[i][j][r], pb + (long)c * 4096 + m);
      }
    }
  }
}

// ---------------------------------------------------------------------------
// combine: out = (p0 + p1) * (1 + sigmoid(ge)), flat over [B][C*N].
// ge (fp16) flat [N][C] memory reinterpreted as [C][W][H] (torch .view).
// ---------------------------------------------------------------------------
__global__ __launch_bounds__(256) void combine_kernel(
    const float* __restrict__ pbuf, const f16* __restrict__ ge,
    float* __restrict__ out) {
  const long NCst = (long)NN * CC;  // 2^20
  long i = ((long)blockIdx.x * 256 + threadIdx.x) * 8;
  int b = (int)(i >> 20);
  long r = i & (NCst - 1);
  const float* p0 = pbuf + (long)(b * 2) * NCst + r;
  const float* p1 = p0 + NCst;
  const f16* g = ge + (long)b * NCst + r;
  float* o = out + i;
  f16x8 gv = *(const f16x8*)(g);
#pragma unroll
  for (int h = 0; h < 2; ++h) {
    float4 a = *(const float4*)(p0 + h * 4);
    float4 c = *(const float4*)(p1 + h * 4);
    float4 u;
    u.x = (a.x + c.x) * (1.f + 1.f / (1.f + __expf(-(float)gv[4 * h + 0])));
    u.y = (a.y + c.y) * (1.f + 1.f / (1.f + __expf(-(float)gv[4 * h + 1])));
    u.z = (a.z + c.z) * (1.f + 1.f / (1.f + __expf(-(float)gv[4 * h + 2])));
    u.w = (a.w + c.w) * (1.f + 1.f / (1.f + __expf(-(float)gv[4 * h + 3])));
    *(float4*)(o + h * 4) = u;
  }
}

// ---------------------------------------------------------------------------
// gate: per row n: s = <q,Wgg[0:256]> + <ge,Wgg[256:512]> + bgg;
//       q += sigmoid(s)*ge. One wave per row. ge fp16.
// ---------------------------------------------------------------------------
__global__ __launch_bounds__(256) void gate_kernel(
    bf16* __restrict__ q, const f16* __restrict__ ge,
    const float* __restrict__ Wgg, const float* __restrict__ bgg) {
  int row = blockIdx.x * 4 + (threadIdx.x >> 6);
  int l = threadIdx.x & 63;
  bf16* qr = q + (long)row * 256;
  const f16* ger = ge + (long)row * 256;
  float s = 0.f;
  float qv[4], gv[4];
#pragma unroll
  for (int i = 0; i < 4; ++i) {
    int o = l + 64 * i;
    qv[i] = (float)qr[o];
    gv[i] = (float)ger[o];
    s += qv[i] * Wgg[o] + gv[i] * Wgg[256 + o];
  }
#pragma unroll
  for (int m = 32; m >= 1; m >>= 1) s += __shfl_xor(s, m, 64);
  float gate = 1.f / (1.f + __expf(-(s + bgg[0])));
#pragma unroll
  for (int i = 0; i < 4; ++i) {
    int o = l + 64 * i;
    qr[o] = (bf16)(qv[i] + gate * gv[i]);
  }
}

// ---------------------------------------------------------------------------
// fallback fp32 softmax (small-ws path)
// ---------------------------------------------------------------------------
__global__ __launch_bounds__(256) void softmax32_kernel(float* __restrict__ attn) {
  long row = blockIdx.x;
  float* p = attn + row * 4096;
  int t = threadIdx.x;
  __shared__ float red[8];
  float4 v[4];
  float mx = -1e30f;
#pragma unroll
  for (int c = 0; c < 4; ++c) {
    v[c] = *(const float4*)(p + c * 1024 + t * 4);
    mx = fmaxf(mx, fmaxf(fmaxf(v[c].x, v[c].y), fmaxf(v[c].z, v[c].w)));
  }
#pragma unroll
  for (int m = 32; m >= 1; m >>= 1) mx = fmaxf(mx, __shfl_xor(mx, m, 64));
  if ((t & 63) == 0) red[t >> 6] = mx;
  __syncthreads();
  mx = fmaxf(fmaxf(red[0], red[1]), fmaxf(red[2], red[3]));
  float sum = 0.f;
#pragma unroll
  for (int c = 0; c < 4; ++c) {
    v[c].x = __expf(v[c].x - mx);
    v[c].y = __expf(v[c].y - mx);
    v[c].z = __expf(v[c].z - mx);
    v[c].w = __expf(v[c].w - mx);
    sum += v[c].x + v[c].y + v[c].z + v[c].w;
  }
#pragma unroll
  for (int m = 32; m >= 1; m >>= 1) sum += __shfl_xor(sum, m, 64);
  if ((t & 63) == 0) red[4 + (t >> 6)] = sum;
  __syncthreads();
  float inv = 1.f / (red[4] + red[5] + red[6] + red[7]);
#pragma unroll
  for (int c = 0; c < 4; ++c) {
    v[c].x *= inv; v[c].y *= inv; v[c].z *= inv; v[c].w *= inv;
    *(float4*)(p + c * 1024 + t * 4) = v[c];
  }
}

// ---------------------------------------------------------------------------
extern "C" void kernel_launch(void* const* d_in, const int* in_sizes, int n_in,
                              void* d_out, int out_size, void* d_ws, size_t ws_size,
                              hipStream_t stream) {
  const float* x    = (const float*)d_in[0];
  const float* geo  = (const float*)d_in[1];
  const float* Wq   = (const float*)d_in[2];
  const float* bq   = (const float*)d_in[3];
  const float* Wk   = (const float*)d_in[4];
  const float* bk   = (const float*)d_in[5];
  const float* Wv   = (const float*)d_in[6];
  const float* bv   = (const float*)d_in[7];
  const float* Wgp  = (const float*)d_in[8];
  const float* bgp  = (const float*)d_in[9];
  const float* Wgg  = (const float*)d_in[10];
  const float* bgg  = (const float*)d_in[11];

  float* out  = (float*)d_out;                    // [B][C][N]
  float* attn = out + (long)BB * CC * NN;         // [B][N][N]

  char* w = (char*)d_ws;
  size_t used = 0;
  auto alloc = [&](size_t bytes) {
    char* p = w + used;
    used += (bytes + 255) & ~(size_t)255;
    return p;
  };
  bf16*  xt   = (bf16*)alloc((size_t)BB * NN * CC * 2);  // [B][N][C]
  bf16*  qn   = (bf16*)alloc((size_t)BB * NN * CC * 2);  // [B][N][O]
  bf16*  kn   = (bf16*)alloc((size_t)BB * NN * CC * 2);  // [B][N][O]
  bf16*  vb   = (bf16*)alloc((size_t)BB * CC * NN * 2);  // [B][O][N]
  f16*   ge   = (f16*)alloc((size_t)BB * NN * CC * 2);   // [B][N][O] fp16
  bf16*  Wall = (bf16*)alloc((size_t)4 * CC * CC * 2);
  // fp16 energy (134MB) + stats + k-split partials — only if ws allows
  size_t abf_bytes   = (size_t)BB * NN * NN * 2;
  size_t pstat_bytes = (size_t)BB * NN * 32 * sizeof(float2);
  size_t pbuf_bytes  = (size_t)BB * 2 * NN * CC * 4;     // 33.5MB
  bool big = (ws_size >= used + abf_bytes + pstat_bytes + pbuf_bytes + 2048);
  f16* abf = nullptr;
  float2* pstat = nullptr;
  float* pbuf = nullptr;
  if (big) {
    abf   = (f16*)alloc(abf_bytes);
    pstat = (float2*)alloc(pstat_bytes);
    pbuf  = (float*)alloc(pbuf_bytes);
  }

  const long NCst = (long)NN * CC;  // 1,048,576
  const long NNst = (long)NN * NN;  // 16,777,216

  // converts + transpose
  cvt_weights_kernel<<<dim3(64, 4), 256, 0, stream>>>(Wq, Wk, Wv, Wgp, Wall);
  transpose_x_kernel<<<dim3(4, 64, BB), 256, 0, stream>>>(x, xt);

  // fused projections: q, ge (direct fp32 geo -> fp16 ge), k, v
  proj_all_kernel<<<dim3(2, 32, BB * 4), 256, 0, stream>>>(
      xt, geo, Wall, bq, bgp, bk, bv, qn, ge, kn, vb);
  // gate update on qn
  gate_kernel<<<(BB * NN) / 4, 256, 0, stream>>>(qn, ge, Wgg, bgg);

  if (big) {
    // energy = qn . kn^T -> fp16 + softmax partials
    energy_kernel<true><<<dim3(32, 16, BB), 512, 0, stream>>>(
        qn, kn, abf, pstat);
    // fused rowstat + softmax + PV (r8 config)
    pv_fused_kernel<true><<<dim3(64, 2, BB), 512, 0, stream>>>(
        vb, abf, pstat, attn, pbuf);
    // combine partials + gate epilogue
    combine_kernel<<<(int)((long)BB * NCst / (256 * 8)), 256, 0, stream>>>(
        pbuf, ge, out);
  } else {
    gemm_nt_lds<0, 0, 0, false, true><<<dim3(32, 32, BB), 256, 0, stream>>>(
        qn, kn, nullptr, attn, nullptr, NN, CC, NCst, NCst, NNst, 0);
    softmax32_kernel<<<BB * NN, 256, 0, stream>>>(attn);
    gemm_nt_lds<0, 1, 0, true, true><<<dim3(32, 2, BB), 256, 0, stream>>>(
        vb, attn, nullptr, out, ge, NN, NN, NCst, NNst, NCst, NCst);
  }
}